// Round 4
// baseline (200.770 us; speedup 1.0000x reference)
//
#include <hip/hip_runtime.h>
#include <hip/hip_bf16.h>

typedef __bf16 bf16_t;
typedef bf16_t bf16x8 __attribute__((ext_vector_type(8)));
typedef bf16_t bf16x4 __attribute__((ext_vector_type(4)));
typedef short  short4v __attribute__((ext_vector_type(4)));
typedef float  f32x4  __attribute__((ext_vector_type(4)));

#define MFMA16(a,b,c) __builtin_amdgcn_mfma_f32_16x16x32_bf16(a, b, c, 0, 0, 0)

constexpr int S = 2048, H = 16, Dh = 64;
constexpr int N = H * Dh;   // 1024
constexpr int K = 1024;     // E
constexpr float QSCALE = 0.125f * 1.4426950408889634f;  // 1/sqrt(64) * log2(e)

static __device__ inline void load_lds16(const bf16_t* g, bf16_t* l) {
  __builtin_amdgcn_global_load_lds(
      (const __attribute__((address_space(1))) void*)g,
      (__attribute__((address_space(3))) void*)l, 16, 0, 0);
}

static __device__ inline ushort f2bb(float x) {
  bf16_t h = (bf16_t)x;
  return __builtin_bit_cast(ushort, h);
}

// ---------------------------------------------------------------------------
// prep: blocks 0..6143 convert X fp32->bf16; blocks 6144..6911 transpose W.
// (unchanged)
// ---------------------------------------------------------------------------
__global__ __launch_bounds__(256) void prep(
    const float* __restrict__ q, const float* __restrict__ k,
    const float* __restrict__ v,
    const float* __restrict__ wq, const float* __restrict__ wk,
    const float* __restrict__ wv,
    bf16_t* __restrict__ xq, bf16_t* __restrict__ xk, bf16_t* __restrict__ xv,
    bf16_t* __restrict__ wtq, bf16_t* __restrict__ wtk, bf16_t* __restrict__ wtv) {
  __shared__ ushort tile[64][68];
  int bx = blockIdx.x, t = threadIdx.x;
  if (bx < 6144) {
    int z = bx >> 11, bb = bx & 2047;
    const float* xi = z == 0 ? q : z == 1 ? k : v;
    bf16_t*      xo = z == 0 ? xq : z == 1 ? xk : xv;
    size_t idx = ((size_t)bb * 256 + t) * 8;
    float4 a = *(const float4*)&xi[idx];
    float4 b = *(const float4*)&xi[idx + 4];
    bf16x8 w;
    w[0] = (bf16_t)a.x; w[1] = (bf16_t)a.y; w[2] = (bf16_t)a.z; w[3] = (bf16_t)a.w;
    w[4] = (bf16_t)b.x; w[5] = (bf16_t)b.y; w[6] = (bf16_t)b.z; w[7] = (bf16_t)b.w;
    *(bf16x8*)&xo[idx] = w;
  } else {
    int zz = bx - 6144;
    int z = zz >> 8, bb = zz & 255;
    const float* wi = z == 0 ? wq : z == 1 ? wk : wv;
    ushort*      wo = (ushort*)(z == 0 ? wtq : z == 1 ? wtk : wtv);
    int k0 = (bb >> 4) * 64, n0 = (bb & 15) * 64;
    for (int i = 0; i < 4; ++i) {
      int idx4 = (i * 256 + t) * 4;
      int r = idx4 >> 6, c = idx4 & 63;
      float4 vv = *(const float4*)&wi[(size_t)(k0 + r) * N + n0 + c];
      tile[r][c] = f2bb(vv.x); tile[r][c + 1] = f2bb(vv.y);
      tile[r][c + 2] = f2bb(vv.z); tile[r][c + 3] = f2bb(vv.w);
    }
    __syncthreads();
    for (int i = 0; i < 4; ++i) {
      int idx4 = (i * 256 + t) * 4;
      int r = idx4 >> 6, c = idx4 & 63;
      ushort4 vv;
      vv.x = tile[c][r]; vv.y = tile[c + 1][r];
      vv.z = tile[c + 2][r]; vv.w = tile[c + 3][r];
      *(ushort4*)&wo[(size_t)(n0 + r) * K + k0 + c] = vv;
    }
  }
}

// ---------------------------------------------------------------------------
// Projection GEMM (unchanged: m97 2-barrier DMA staging, XOR swizzle,
// LDS-staged coalesced epilogue).
// ---------------------------------------------------------------------------
__global__ __launch_bounds__(256) void proj_gemm(
    const bf16_t* __restrict__ xq, const bf16_t* __restrict__ xk,
    const bf16_t* __restrict__ xv,
    const bf16_t* __restrict__ wtq, const bf16_t* __restrict__ wtk,
    const bf16_t* __restrict__ wtv,
    const float* __restrict__ bq, const float* __restrict__ bk,
    const float* __restrict__ bv,
    bf16_t* __restrict__ qh, bf16_t* __restrict__ kh, bf16_t* __restrict__ vt) {
  int mode = blockIdx.z;
  const bf16_t* X  = mode == 0 ? xq  : mode == 1 ? xk  : wtv;  // A rows
  const bf16_t* Wt = mode == 0 ? wtq : mode == 1 ? wtk : xv;   // B rows
  const float*  Bi = mode == 0 ? bq  : mode == 1 ? bk  : bv;

  __shared__ __align__(16) bf16_t smem[17408];   // 34.8 KB
  bf16_t (*Ash)[64] = (bf16_t(*)[64])smem;
  bf16_t (*Bsh)[64] = (bf16_t(*)[64])(smem + 8192);
  bf16_t* Cs = smem;

  int tid = threadIdx.x;
  int wave = tid >> 6, lane = tid & 63;
  int lr = lane & 15, lg = lane >> 4;
  int lrow = lane >> 3, lchunk = lane & 7;
  int m0 = (mode < 2 ? blockIdx.y : blockIdx.x) * 128;
  int n0 = (mode < 2 ? blockIdx.x : blockIdx.y) * 128;
  int wm = (wave >> 1) * 64, wn = (wave & 1) * 64;

  f32x4 acc[4][4];
  for (int i = 0; i < 4; ++i)
    for (int j = 0; j < 4; ++j) acc[i][j] = (f32x4){0.f, 0.f, 0.f, 0.f};

  for (int ko = 0; ko < K / 64; ++ko) {
    __syncthreads();
    for (int j = 0; j < 4; ++j) {
      int r = wave * 32 + j * 8 + lrow;
      int gc = (lchunk ^ (r & 7)) * 8;
      load_lds16(&X [(size_t)(m0 + r) * K + ko * 64 + gc], &Ash[r][lchunk * 8]);
      load_lds16(&Wt[(size_t)(n0 + r) * K + ko * 64 + gc], &Bsh[r][lchunk * 8]);
    }
    __syncthreads();
    for (int kk = 0; kk < 2; ++kk) {
      bf16x8 af[4], bfr[4];
      for (int i = 0; i < 4; ++i) {
        int rr = wm + i * 16 + lr;
        af[i] = *(const bf16x8*)&Ash[rr][(((kk << 2) | lg) ^ (rr & 7)) * 8];
      }
      for (int j = 0; j < 4; ++j) {
        int rr = wn + j * 16 + lr;
        bfr[j] = *(const bf16x8*)&Bsh[rr][(((kk << 2) | lg) ^ (rr & 7)) * 8];
      }
      for (int i = 0; i < 4; ++i)
        for (int j = 0; j < 4; ++j)
          acc[i][j] = MFMA16(af[i], bfr[j], acc[i][j]);
    }
  }

  float badd[4][4][4];
  if (mode < 2) {
    float bvv[4];
    for (int j = 0; j < 4; ++j) bvv[j] = Bi[n0 + wn + j * 16 + lr];
    for (int i = 0; i < 4; ++i)
      for (int j = 0; j < 4; ++j)
        for (int r = 0; r < 4; ++r) badd[i][j][r] = bvv[j];
  } else {
    for (int i = 0; i < 4; ++i)
      for (int r = 0; r < 4; ++r) {
        float bm = Bi[m0 + wm + i * 16 + lg * 4 + r];
        for (int j = 0; j < 4; ++j) badd[i][j][r] = bm;
      }
  }

  __syncthreads();
  for (int i = 0; i < 4; ++i)
    for (int j = 0; j < 4; ++j)
      for (int r = 0; r < 4; ++r) {
        float vvv = acc[i][j][r] + badd[i][j][r];
        if (mode == 0) vvv *= QSCALE;
        Cs[(size_t)(wm + i * 16 + lg * 4 + r) * 136 + wn + j * 16 + lr] = (bf16_t)vvv;
      }
  __syncthreads();

  bf16_t* o = mode == 0 ? qh : mode == 1 ? kh : vt;
  for (int p = 0; p < 8; ++p) {
    int idx = p * 256 + tid;
    int row = idx >> 4, ch = idx & 15;
    bf16x8 vv = *(const bf16x8*)&Cs[(size_t)row * 136 + ch * 8];
    size_t dst;
    if (mode < 2) {
      int m_g = m0 + row, n_g = n0 + ch * 8;
      int b = m_g >> 11, s = m_g & 2047;
      int h = n_g >> 6, d = n_g & 63;
      dst = (((size_t)(b * 16 + h) * 2048) + s) * 64 + d;
    } else {
      int w_g = m0 + row, t_g = n0 + ch * 8;
      int b = t_g >> 11, s = t_g & 2047;
      dst = ((size_t)(b * 1024 + w_g)) * 2048 + s;
    }
    *(uint4*)&o[dst] = __builtin_bit_cast(uint4, vv);
  }
}

// ---------------------------------------------------------------------------
// Flash attention v8: v7's verified compute dataflow + two stall fixes:
//   * LDS DOUBLE-BUFFER (64 KB): write tile i+1 into buf^1 while computing
//     tile i from buf -> ONE barrier/iter instead of two (16 barrier-drains
//     removed).  RAW: writes of tile i+1 are visible at iter i+1's top
//     barrier.  WAR: reads of buf^1 (iter i-1) retired before iter i's top
//     barrier, writes of tile i+1 come after it.  2 blocks/CU still fit
//     (128 KB <= 160 KB).
//   * XCD-CHUNKED block mapping: hw round-robins flat id across 8 XCDs;
//     logical = (bid&7)*64 + bid>>3 gives each XCD 64 consecutive logical
//     blocks = 4 heads -> 2 MB K/V resident in its 4 MB L2 (R3 FETCH 69.7 MB
//     vs ~48 MB compulsory showed cross-XCD K/V re-fetch; prefetch misses
//     ~900cyc -> L2 hits ~200cyc).  512%8==0 -> bijective.
// ---------------------------------------------------------------------------
__global__ __launch_bounds__(512, 2) void attn(
    const bf16_t* __restrict__ qh, const bf16_t* __restrict__ kh,
    const bf16_t* __restrict__ vt, float* __restrict__ out) {
  // 64 KB: 2 bufs x 2 halves x (kt 8KB + vs 8KB); merge overlay (33280 B)
  // reuses the front of the staging space after the final barrier.
  __shared__ __align__(16) bf16_t smem[32768];

  int tid = threadIdx.x, wave = tid >> 6, lane = tid & 63;
  int lr = lane & 15, lg = lane >> 4;
  int half = wave >> 2, w4 = wave & 3;

  int bid = blockIdx.x;
  int logical = (bid & 7) * 64 + (bid >> 3);
  int bh = logical >> 4;
  int q0 = (logical & 15) * 128 + w4 * 32;

  bf16_t* kt0 = smem + half * 8192;     // buffer-0 K base for this half
  // vs = kt + 4096; buffer stride = 16384 elements (32 KB)

  const bf16_t* qg = qh + (size_t)bh * S * Dh;
  const bf16_t* kg = kh + (size_t)bh * S * Dh;
  const bf16_t* vg = vt + (size_t)bh * Dh * S;

  bf16x8 bqf[2][2];
#pragma unroll
  for (int ms = 0; ms < 2; ++ms)
#pragma unroll
    for (int kk = 0; kk < 2; ++kk)
      bqf[ms][kk] = *(const bf16x8*)
          &qg[(size_t)(q0 + ms * 16 + lr) * 64 + kk * 32 + lg * 8];

  bf16x8 ones8;
#pragma unroll
  for (int j = 0; j < 8; ++j) ones8[j] = (bf16_t)1.0f;

  f32x4 o_acc[2][4], lacc[2];
#pragma unroll
  for (int ms = 0; ms < 2; ++ms) {
    lacc[ms] = (f32x4){0.f, 0.f, 0.f, 0.f};
#pragma unroll
    for (int dt = 0; dt < 4; ++dt) o_acc[ms][dt] = (f32x4){0.f, 0.f, 0.f, 0.f};
  }

  // staging geometry within the half (256 threads cover 64 rows x 8 chunks,
  // two 16B slots per thread per matrix)
  int lrow = lane >> 3, lchunk = lane & 7;
  int srow0 = w4 * 16 + lrow;
  int srow1 = srow0 + 8;
  int sgc = (lchunk ^ (srow0 & 7)) * 8;   // (srow1&7)==(srow0&7)
  int ld0 = srow0 * 64 + lchunk * 8;
  int ld1 = ld0 + 512;                    // +8 rows

  int cb = half * (S / 2);                // this half's kv col base

  // prologue: tile 0 -> regs -> buf0; then prefetch tile 1 into regs
  uint4 kr0 = *(const uint4*)&kg[(size_t)(cb + srow0) * 64 + sgc];
  uint4 kr1 = *(const uint4*)&kg[(size_t)(cb + srow1) * 64 + sgc];
  uint4 vr0 = *(const uint4*)&vg[(size_t)srow0 * S + cb + sgc];
  uint4 vr1 = *(const uint4*)&vg[(size_t)srow1 * S + cb + sgc];
  *(uint4*)&kt0[ld0] = kr0;              // ds_write waits vmcnt for OWN loads
  *(uint4*)&kt0[ld1] = kr1;
  *(uint4*)&kt0[4096 + ld0] = vr0;
  *(uint4*)&kt0[4096 + ld1] = vr1;
  {
    int sk1 = cb + 64;
    kr0 = *(const uint4*)&kg[(size_t)(sk1 + srow0) * 64 + sgc];
    kr1 = *(const uint4*)&kg[(size_t)(sk1 + srow1) * 64 + sgc];
    vr0 = *(const uint4*)&vg[(size_t)srow0 * S + sk1 + sgc];
    vr1 = *(const uint4*)&vg[(size_t)srow1 * S + sk1 + sgc];
  }

  int sw = lr & 7, p4 = (lg & 1) * 4;

  constexpr int NITH = (S / 2) / 64;      // 16
  for (int it = 0; it < NITH; ++it) {
    __syncthreads();                      // buf[it&1] ready; buf^1 reads retired
    if (it + 1 < NITH) {
      int wb = ((it + 1) & 1) * 16384;    // write NEXT tile into other buffer
      *(uint4*)&kt0[wb + ld0] = kr0;
      *(uint4*)&kt0[wb + ld1] = kr1;
      *(uint4*)&kt0[wb + 4096 + ld0] = vr0;
      *(uint4*)&kt0[wb + 4096 + ld1] = vr1;
      if (it + 2 < NITH) {                // prefetch tile i+2 into regs
        int sk = cb + (it + 2) * 64;
        kr0 = *(const uint4*)&kg[(size_t)(sk + srow0) * 64 + sgc];
        kr1 = *(const uint4*)&kg[(size_t)(sk + srow1) * 64 + sgc];
        vr0 = *(const uint4*)&vg[(size_t)srow0 * S + sk + sgc];
        vr1 = *(const uint4*)&vg[(size_t)srow1 * S + sk + sgc];
      }
    }
    const bf16_t* ktr = kt0 + (it & 1) * 16384;
    const bf16_t* vsr = ktr + 4096;

    // QK^T (swapped operands: A=K, B=Q -> lane holds scores for q-row lr),
    // processed in two tp groups of 32 k-cols; st/ak transient per group.
    // pa8[ms][tp] slot j holds P[q=lr][k = tp*32 + (j>>2)*16 + lg*4 + (j&3)]
    bf16x8 pa8[2][2];
#pragma unroll
    for (int tp = 0; tp < 2; ++tp) {
      f32x4 st[2][2];
#pragma unroll
      for (int ms = 0; ms < 2; ++ms)
#pragma unroll
        for (int ts = 0; ts < 2; ++ts) st[ms][ts] = (f32x4){0.f, 0.f, 0.f, 0.f};
#pragma unroll
      for (int ts = 0; ts < 2; ++ts) {
        int t = tp * 2 + ts;
        const bf16_t* krow = &ktr[(t * 16 + lr) * 64];
        bf16x8 ak0 = *(const bf16x8*)&krow[(lg ^ sw) * 8];
        bf16x8 ak1 = *(const bf16x8*)&krow[((4 + lg) ^ sw) * 8];
#pragma unroll
        for (int ms = 0; ms < 2; ++ms) {
          st[ms][ts] = MFMA16(ak0, bqf[ms][0], st[ms][ts]);
          st[ms][ts] = MFMA16(ak1, bqf[ms][1], st[ms][ts]);
        }
      }
#pragma unroll
      for (int ms = 0; ms < 2; ++ms)
#pragma unroll
        for (int r = 0; r < 4; ++r) {
          pa8[ms][tp][r]     = (bf16_t)__builtin_amdgcn_exp2f(st[ms][0][r]);
          pa8[ms][tp][r + 4] = (bf16_t)__builtin_amdgcn_exp2f(st[ms][1][r]);
        }
    }

    // PV at full k=32 rate; V fragments built transiently per dt, shared by
    // both Q-tiles.
#pragma unroll
    for (int tp = 0; tp < 2; ++tp) {
      int g0 = tp * 4 + (lg >> 1);
#pragma unroll
      for (int dt = 0; dt < 4; ++dt) {
        const bf16_t* vrow = &vsr[(dt * 16 + lr) * 64];
        bf16x4 lo = *(const bf16x4*)&vrow[((g0      ^ sw) * 8) + p4];
        bf16x4 hi = *(const bf16x4*)&vrow[(((g0 + 2) ^ sw) * 8) + p4];
        bf16x8 bb;
#pragma unroll
        for (int j = 0; j < 4; ++j) { bb[j] = lo[j]; bb[j + 4] = hi[j]; }
#pragma unroll
        for (int ms = 0; ms < 2; ++ms)
          o_acc[ms][dt] = MFMA16(pa8[ms][tp], bb, o_acc[ms][dt]);
      }
#pragma unroll
      for (int ms = 0; ms < 2; ++ms)
        lacc[ms] = MFMA16(pa8[ms][tp], ones8, lacc[ms]);
    }
  }

  // ---- merge halves via LDS overlay (reuses staging space) ----
  __syncthreads();                        // all staging reads/writes retired
  float* mo = (float*)smem;               // [8 q-subtiles][16 rows][64 cols]
  float* ls = mo + 8 * 16 * 64;           // [8][16] rowsums

  if (half == 1) {
#pragma unroll
    for (int ms = 0; ms < 2; ++ms)
#pragma unroll
      for (int r = 0; r < 4; ++r) {
        int row = (w4 * 2 + ms) * 16 + lg * 4 + r;
#pragma unroll
        for (int dt = 0; dt < 4; ++dt)
          mo[row * 64 + dt * 16 + lr] = o_acc[ms][dt][r];
        if (lr == 0) ls[row] = lacc[ms][r];
      }
  }
  __syncthreads();
  if (half == 0) {
    int b = bh >> 4, hh = bh & 15;
#pragma unroll
    for (int ms = 0; ms < 2; ++ms)
#pragma unroll
      for (int r = 0; r < 4; ++r) {
        int row = (w4 * 2 + ms) * 16 + lg * 4 + r;
        float inv = 1.f / (lacc[ms][r] + ls[row]);
        int s_row = q0 + ms * 16 + lg * 4 + r;
        size_t base = ((size_t)(b * S + s_row)) * 1024 + hh * 64;
#pragma unroll
        for (int dt = 0; dt < 4; ++dt)
          out[base + dt * 16 + lr] =
              (o_acc[ms][dt][r] + mo[row * 64 + dt * 16 + lr]) * inv;
      }
  }
}

// ---------------------------------------------------------------------------
extern "C" void kernel_launch(void* const* d_in, const int* in_sizes, int n_in,
                              void* d_out, int out_size, void* d_ws, size_t ws_size,
                              hipStream_t stream) {
  const float* q  = (const float*)d_in[0];
  const float* k  = (const float*)d_in[1];
  const float* v  = (const float*)d_in[2];
  const float* wq = (const float*)d_in[3];
  const float* bq = (const float*)d_in[4];
  const float* wk = (const float*)d_in[5];
  const float* bk = (const float*)d_in[6];
  const float* wv = (const float*)d_in[7];
  const float* bv = (const float*)d_in[8];

  bf16_t* ws  = (bf16_t*)d_ws;
  constexpr size_t MW = (size_t)1 << 20;
  constexpr size_t MX = (size_t)4096 * 1024;
  bf16_t* wtq = ws;
  bf16_t* wtk = wtq + MW;
  bf16_t* wtv = wtk + MW;
  bf16_t* xq  = wtv + MW;
  bf16_t* xk  = xq + MX;
  bf16_t* xv  = xk + MX;
  bf16_t* qhd = xv + MX;
  bf16_t* khd = qhd + MX;
  bf16_t* vtd = khd + MX;
  float* out  = (float*)d_out;

  prep<<<6912, 256, 0, stream>>>(q, k, v, wq, wk, wv,
                                 xq, xk, xv, wtq, wtk, wtv);
  proj_gemm<<<dim3(8, 32, 3), 256, 0, stream>>>(xq, xk, xv, wtq, wtk, wtv,
                                                bq, bk, bv, qhd, khd, vtd);
  attn<<<512, 512, 0, stream>>>(qhd, khd, vtd, out);
}

// Round 5
// 196.860 us; speedup vs baseline: 1.0199x; 1.0199x over previous
//
#include <hip/hip_runtime.h>
#include <hip/hip_bf16.h>

typedef __bf16 bf16_t;
typedef bf16_t bf16x8 __attribute__((ext_vector_type(8)));
typedef bf16_t bf16x4 __attribute__((ext_vector_type(4)));
typedef short  short4v __attribute__((ext_vector_type(4)));
typedef float  f32x4  __attribute__((ext_vector_type(4)));

#define MFMA16(a,b,c) __builtin_amdgcn_mfma_f32_16x16x32_bf16(a, b, c, 0, 0, 0)

constexpr int S = 2048, H = 16, Dh = 64;
constexpr int N = H * Dh;   // 1024
constexpr int K = 1024;     // E
constexpr float QSCALE = 0.125f * 1.4426950408889634f;  // 1/sqrt(64) * log2(e)

static __device__ inline void load_lds16(const bf16_t* g, bf16_t* l) {
  __builtin_amdgcn_global_load_lds(
      (const __attribute__((address_space(1))) void*)g,
      (__attribute__((address_space(3))) void*)l, 16, 0, 0);
}

static __device__ inline ushort f2bb(float x) {
  bf16_t h = (bf16_t)x;
  return __builtin_bit_cast(ushort, h);
}

// ---------------------------------------------------------------------------
// prep: blocks 0..6143 convert X fp32->bf16; blocks 6144..6911 transpose W.
// (unchanged)
// ---------------------------------------------------------------------------
__global__ __launch_bounds__(256) void prep(
    const float* __restrict__ q, const float* __restrict__ k,
    const float* __restrict__ v,
    const float* __restrict__ wq, const float* __restrict__ wk,
    const float* __restrict__ wv,
    bf16_t* __restrict__ xq, bf16_t* __restrict__ xk, bf16_t* __restrict__ xv,
    bf16_t* __restrict__ wtq, bf16_t* __restrict__ wtk, bf16_t* __restrict__ wtv) {
  __shared__ ushort tile[64][68];
  int bx = blockIdx.x, t = threadIdx.x;
  if (bx < 6144) {
    int z = bx >> 11, bb = bx & 2047;
    const float* xi = z == 0 ? q : z == 1 ? k : v;
    bf16_t*      xo = z == 0 ? xq : z == 1 ? xk : xv;
    size_t idx = ((size_t)bb * 256 + t) * 8;
    float4 a = *(const float4*)&xi[idx];
    float4 b = *(const float4*)&xi[idx + 4];
    bf16x8 w;
    w[0] = (bf16_t)a.x; w[1] = (bf16_t)a.y; w[2] = (bf16_t)a.z; w[3] = (bf16_t)a.w;
    w[4] = (bf16_t)b.x; w[5] = (bf16_t)b.y; w[6] = (bf16_t)b.z; w[7] = (bf16_t)b.w;
    *(bf16x8*)&xo[idx] = w;
  } else {
    int zz = bx - 6144;
    int z = zz >> 8, bb = zz & 255;
    const float* wi = z == 0 ? wq : z == 1 ? wk : wv;
    ushort*      wo = (ushort*)(z == 0 ? wtq : z == 1 ? wtk : wtv);
    int k0 = (bb >> 4) * 64, n0 = (bb & 15) * 64;
    for (int i = 0; i < 4; ++i) {
      int idx4 = (i * 256 + t) * 4;
      int r = idx4 >> 6, c = idx4 & 63;
      float4 vv = *(const float4*)&wi[(size_t)(k0 + r) * N + n0 + c];
      tile[r][c] = f2bb(vv.x); tile[r][c + 1] = f2bb(vv.y);
      tile[r][c + 2] = f2bb(vv.z); tile[r][c + 3] = f2bb(vv.w);
    }
    __syncthreads();
    for (int i = 0; i < 4; ++i) {
      int idx4 = (i * 256 + t) * 4;
      int r = idx4 >> 6, c = idx4 & 63;
      ushort4 vv;
      vv.x = tile[c][r]; vv.y = tile[c + 1][r];
      vv.z = tile[c + 2][r]; vv.w = tile[c + 3][r];
      *(ushort4*)&wo[(size_t)(n0 + r) * K + k0 + c] = vv;
    }
  }
}

// ---------------------------------------------------------------------------
// Projection GEMM (m97 2-barrier DMA staging, XOR swizzle, LDS-staged
// coalesced epilogue) + R5: XCD-CHUNKED BLOCK MAPPING.
//   R4 counters: FETCH 101.4 MB vs ~30 MB compulsory reads -- the 8 blocks
//   sharing a 256 KB A-panel (same y, x=0..7, dispatched consecutively) land
//   on 8 different XCDs, so every panel is fetched once per XCD L2.
//   Fix: flat 768-block grid; logical = (bid&7)*96 + (bid>>3) gives each XCD
//   96 consecutive logicals = 12 complete A-panel groups + the 2 MB W panel,
//   all L2-resident (96 blocks = one XCD's residency at 3 blocks/CU).
//   768 % 8 == 0 -> bijective.  Compute code unchanged.
// ---------------------------------------------------------------------------
__global__ __launch_bounds__(256) void proj_gemm(
    const bf16_t* __restrict__ xq, const bf16_t* __restrict__ xk,
    const bf16_t* __restrict__ xv,
    const bf16_t* __restrict__ wtq, const bf16_t* __restrict__ wtk,
    const bf16_t* __restrict__ wtv,
    const float* __restrict__ bq, const float* __restrict__ bk,
    const float* __restrict__ bv,
    bf16_t* __restrict__ qh, bf16_t* __restrict__ kh, bf16_t* __restrict__ vt) {
  int bid = blockIdx.x;                       // 0..767
  int logical = (bid & 7) * 96 + (bid >> 3);  // XCD-chunked, bijective
  int mode = logical >> 8;                    // 256 logicals per mode
  int rem = logical & 255;
  int gx = rem & 7;                           // N-tile (fastest within XCD)
  int gy = rem >> 3;                          // M-tile

  const bf16_t* X  = mode == 0 ? xq  : mode == 1 ? xk  : wtv;  // A rows
  const bf16_t* Wt = mode == 0 ? wtq : mode == 1 ? wtk : xv;   // B rows
  const float*  Bi = mode == 0 ? bq  : mode == 1 ? bk  : bv;

  __shared__ __align__(16) bf16_t smem[17408];   // 34.8 KB
  bf16_t (*Ash)[64] = (bf16_t(*)[64])smem;
  bf16_t (*Bsh)[64] = (bf16_t(*)[64])(smem + 8192);
  bf16_t* Cs = smem;

  int tid = threadIdx.x;
  int wave = tid >> 6, lane = tid & 63;
  int lr = lane & 15, lg = lane >> 4;
  int lrow = lane >> 3, lchunk = lane & 7;
  int m0 = (mode < 2 ? gy : gx) * 128;
  int n0 = (mode < 2 ? gx : gy) * 128;
  int wm = (wave >> 1) * 64, wn = (wave & 1) * 64;

  f32x4 acc[4][4];
  for (int i = 0; i < 4; ++i)
    for (int j = 0; j < 4; ++j) acc[i][j] = (f32x4){0.f, 0.f, 0.f, 0.f};

  for (int ko = 0; ko < K / 64; ++ko) {
    __syncthreads();
    for (int j = 0; j < 4; ++j) {
      int r = wave * 32 + j * 8 + lrow;
      int gc = (lchunk ^ (r & 7)) * 8;
      load_lds16(&X [(size_t)(m0 + r) * K + ko * 64 + gc], &Ash[r][lchunk * 8]);
      load_lds16(&Wt[(size_t)(n0 + r) * K + ko * 64 + gc], &Bsh[r][lchunk * 8]);
    }
    __syncthreads();
    for (int kk = 0; kk < 2; ++kk) {
      bf16x8 af[4], bfr[4];
      for (int i = 0; i < 4; ++i) {
        int rr = wm + i * 16 + lr;
        af[i] = *(const bf16x8*)&Ash[rr][(((kk << 2) | lg) ^ (rr & 7)) * 8];
      }
      for (int j = 0; j < 4; ++j) {
        int rr = wn + j * 16 + lr;
        bfr[j] = *(const bf16x8*)&Bsh[rr][(((kk << 2) | lg) ^ (rr & 7)) * 8];
      }
      for (int i = 0; i < 4; ++i)
        for (int j = 0; j < 4; ++j)
          acc[i][j] = MFMA16(af[i], bfr[j], acc[i][j]);
    }
  }

  float badd[4][4][4];
  if (mode < 2) {
    float bvv[4];
    for (int j = 0; j < 4; ++j) bvv[j] = Bi[n0 + wn + j * 16 + lr];
    for (int i = 0; i < 4; ++i)
      for (int j = 0; j < 4; ++j)
        for (int r = 0; r < 4; ++r) badd[i][j][r] = bvv[j];
  } else {
    for (int i = 0; i < 4; ++i)
      for (int r = 0; r < 4; ++r) {
        float bm = Bi[m0 + wm + i * 16 + lg * 4 + r];
        for (int j = 0; j < 4; ++j) badd[i][j][r] = bm;
      }
  }

  __syncthreads();
  for (int i = 0; i < 4; ++i)
    for (int j = 0; j < 4; ++j)
      for (int r = 0; r < 4; ++r) {
        float vvv = acc[i][j][r] + badd[i][j][r];
        if (mode == 0) vvv *= QSCALE;
        Cs[(size_t)(wm + i * 16 + lg * 4 + r) * 136 + wn + j * 16 + lr] = (bf16_t)vvv;
      }
  __syncthreads();

  bf16_t* o = mode == 0 ? qh : mode == 1 ? kh : vt;
  for (int p = 0; p < 8; ++p) {
    int idx = p * 256 + tid;
    int row = idx >> 4, ch = idx & 15;
    bf16x8 vv = *(const bf16x8*)&Cs[(size_t)row * 136 + ch * 8];
    size_t dst;
    if (mode < 2) {
      int m_g = m0 + row, n_g = n0 + ch * 8;
      int b = m_g >> 11, s = m_g & 2047;
      int h = n_g >> 6, d = n_g & 63;
      dst = (((size_t)(b * 16 + h) * 2048) + s) * 64 + d;
    } else {
      int w_g = m0 + row, t_g = n0 + ch * 8;
      int b = t_g >> 11, s = t_g & 2047;
      dst = ((size_t)(b * 1024 + w_g)) * 2048 + s;
    }
    *(uint4*)&o[dst] = __builtin_bit_cast(uint4, vv);
  }
}

// ---------------------------------------------------------------------------
// Flash attention v8 (unchanged from R4: KV-split halves, LDS double-buffer
// with one barrier/iter, XCD-chunked block mapping, paired K=32 PV).
// ---------------------------------------------------------------------------
__global__ __launch_bounds__(512, 2) void attn(
    const bf16_t* __restrict__ qh, const bf16_t* __restrict__ kh,
    const bf16_t* __restrict__ vt, float* __restrict__ out) {
  // 64 KB: 2 bufs x 2 halves x (kt 8KB + vs 8KB); merge overlay (33280 B)
  // reuses the front of the staging space after the final barrier.
  __shared__ __align__(16) bf16_t smem[32768];

  int tid = threadIdx.x, wave = tid >> 6, lane = tid & 63;
  int lr = lane & 15, lg = lane >> 4;
  int half = wave >> 2, w4 = wave & 3;

  int bid = blockIdx.x;
  int logical = (bid & 7) * 64 + (bid >> 3);
  int bh = logical >> 4;
  int q0 = (logical & 15) * 128 + w4 * 32;

  bf16_t* kt0 = smem + half * 8192;     // buffer-0 K base for this half
  // vs = kt + 4096; buffer stride = 16384 elements (32 KB)

  const bf16_t* qg = qh + (size_t)bh * S * Dh;
  const bf16_t* kg = kh + (size_t)bh * S * Dh;
  const bf16_t* vg = vt + (size_t)bh * Dh * S;

  bf16x8 bqf[2][2];
#pragma unroll
  for (int ms = 0; ms < 2; ++ms)
#pragma unroll
    for (int kk = 0; kk < 2; ++kk)
      bqf[ms][kk] = *(const bf16x8*)
          &qg[(size_t)(q0 + ms * 16 + lr) * 64 + kk * 32 + lg * 8];

  bf16x8 ones8;
#pragma unroll
  for (int j = 0; j < 8; ++j) ones8[j] = (bf16_t)1.0f;

  f32x4 o_acc[2][4], lacc[2];
#pragma unroll
  for (int ms = 0; ms < 2; ++ms) {
    lacc[ms] = (f32x4){0.f, 0.f, 0.f, 0.f};
#pragma unroll
    for (int dt = 0; dt < 4; ++dt) o_acc[ms][dt] = (f32x4){0.f, 0.f, 0.f, 0.f};
  }

  // staging geometry within the half (256 threads cover 64 rows x 8 chunks,
  // two 16B slots per thread per matrix)
  int lrow = lane >> 3, lchunk = lane & 7;
  int srow0 = w4 * 16 + lrow;
  int srow1 = srow0 + 8;
  int sgc = (lchunk ^ (srow0 & 7)) * 8;   // (srow1&7)==(srow0&7)
  int ld0 = srow0 * 64 + lchunk * 8;
  int ld1 = ld0 + 512;                    // +8 rows

  int cb = half * (S / 2);                // this half's kv col base

  // prologue: tile 0 -> regs -> buf0; then prefetch tile 1 into regs
  uint4 kr0 = *(const uint4*)&kg[(size_t)(cb + srow0) * 64 + sgc];
  uint4 kr1 = *(const uint4*)&kg[(size_t)(cb + srow1) * 64 + sgc];
  uint4 vr0 = *(const uint4*)&vg[(size_t)srow0 * S + cb + sgc];
  uint4 vr1 = *(const uint4*)&vg[(size_t)srow1 * S + cb + sgc];
  *(uint4*)&kt0[ld0] = kr0;              // ds_write waits vmcnt for OWN loads
  *(uint4*)&kt0[ld1] = kr1;
  *(uint4*)&kt0[4096 + ld0] = vr0;
  *(uint4*)&kt0[4096 + ld1] = vr1;
  {
    int sk1 = cb + 64;
    kr0 = *(const uint4*)&kg[(size_t)(sk1 + srow0) * 64 + sgc];
    kr1 = *(const uint4*)&kg[(size_t)(sk1 + srow1) * 64 + sgc];
    vr0 = *(const uint4*)&vg[(size_t)srow0 * S + sk1 + sgc];
    vr1 = *(const uint4*)&vg[(size_t)srow1 * S + sk1 + sgc];
  }

  int sw = lr & 7, p4 = (lg & 1) * 4;

  constexpr int NITH = (S / 2) / 64;      // 16
  for (int it = 0; it < NITH; ++it) {
    __syncthreads();                      // buf[it&1] ready; buf^1 reads retired
    if (it + 1 < NITH) {
      int wb = ((it + 1) & 1) * 16384;    // write NEXT tile into other buffer
      *(uint4*)&kt0[wb + ld0] = kr0;
      *(uint4*)&kt0[wb + ld1] = kr1;
      *(uint4*)&kt0[wb + 4096 + ld0] = vr0;
      *(uint4*)&kt0[wb + 4096 + ld1] = vr1;
      if (it + 2 < NITH) {                // prefetch tile i+2 into regs
        int sk = cb + (it + 2) * 64;
        kr0 = *(const uint4*)&kg[(size_t)(sk + srow0) * 64 + sgc];
        kr1 = *(const uint4*)&kg[(size_t)(sk + srow1) * 64 + sgc];
        vr0 = *(const uint4*)&vg[(size_t)srow0 * S + sk + sgc];
        vr1 = *(const uint4*)&vg[(size_t)srow1 * S + sk + sgc];
      }
    }
    const bf16_t* ktr = kt0 + (it & 1) * 16384;
    const bf16_t* vsr = ktr + 4096;

    // QK^T (swapped operands: A=K, B=Q -> lane holds scores for q-row lr),
    // processed in two tp groups of 32 k-cols; st/ak transient per group.
    // pa8[ms][tp] slot j holds P[q=lr][k = tp*32 + (j>>2)*16 + lg*4 + (j&3)]
    bf16x8 pa8[2][2];
#pragma unroll
    for (int tp = 0; tp < 2; ++tp) {
      f32x4 st[2][2];
#pragma unroll
      for (int ms = 0; ms < 2; ++ms)
#pragma unroll
        for (int ts = 0; ts < 2; ++ts) st[ms][ts] = (f32x4){0.f, 0.f, 0.f, 0.f};
#pragma unroll
      for (int ts = 0; ts < 2; ++ts) {
        int t = tp * 2 + ts;
        const bf16_t* krow = &ktr[(t * 16 + lr) * 64];
        bf16x8 ak0 = *(const bf16x8*)&krow[(lg ^ sw) * 8];
        bf16x8 ak1 = *(const bf16x8*)&krow[((4 + lg) ^ sw) * 8];
#pragma unroll
        for (int ms = 0; ms < 2; ++ms) {
          st[ms][ts] = MFMA16(ak0, bqf[ms][0], st[ms][ts]);
          st[ms][ts] = MFMA16(ak1, bqf[ms][1], st[ms][ts]);
        }
      }
#pragma unroll
      for (int ms = 0; ms < 2; ++ms)
#pragma unroll
        for (int r = 0; r < 4; ++r) {
          pa8[ms][tp][r]     = (bf16_t)__builtin_amdgcn_exp2f(st[ms][0][r]);
          pa8[ms][tp][r + 4] = (bf16_t)__builtin_amdgcn_exp2f(st[ms][1][r]);
        }
    }

    // PV at full k=32 rate; V fragments built transiently per dt, shared by
    // both Q-tiles.
#pragma unroll
    for (int tp = 0; tp < 2; ++tp) {
      int g0 = tp * 4 + (lg >> 1);
#pragma unroll
      for (int dt = 0; dt < 4; ++dt) {
        const bf16_t* vrow = &vsr[(dt * 16 + lr) * 64];
        bf16x4 lo = *(const bf16x4*)&vrow[((g0      ^ sw) * 8) + p4];
        bf16x4 hi = *(const bf16x4*)&vrow[(((g0 + 2) ^ sw) * 8) + p4];
        bf16x8 bb;
#pragma unroll
        for (int j = 0; j < 4; ++j) { bb[j] = lo[j]; bb[j + 4] = hi[j]; }
#pragma unroll
        for (int ms = 0; ms < 2; ++ms)
          o_acc[ms][dt] = MFMA16(pa8[ms][tp], bb, o_acc[ms][dt]);
      }
#pragma unroll
      for (int ms = 0; ms < 2; ++ms)
        lacc[ms] = MFMA16(pa8[ms][tp], ones8, lacc[ms]);
    }
  }

  // ---- merge halves via LDS overlay (reuses staging space) ----
  __syncthreads();                        // all staging reads/writes retired
  float* mo = (float*)smem;               // [8 q-subtiles][16 rows][64 cols]
  float* ls = mo + 8 * 16 * 64;           // [8][16] rowsums

  if (half == 1) {
#pragma unroll
    for (int ms = 0; ms < 2; ++ms)
#pragma unroll
      for (int r = 0; r < 4; ++r) {
        int row = (w4 * 2 + ms) * 16 + lg * 4 + r;
#pragma unroll
        for (int dt = 0; dt < 4; ++dt)
          mo[row * 64 + dt * 16 + lr] = o_acc[ms][dt][r];
        if (lr == 0) ls[row] = lacc[ms][r];
      }
  }
  __syncthreads();
  if (half == 0) {
    int b = bh >> 4, hh = bh & 15;
#pragma unroll
    for (int ms = 0; ms < 2; ++ms)
#pragma unroll
      for (int r = 0; r < 4; ++r) {
        int row = (w4 * 2 + ms) * 16 + lg * 4 + r;
        float inv = 1.f / (lacc[ms][r] + ls[row]);
        int s_row = q0 + ms * 16 + lg * 4 + r;
        size_t base = ((size_t)(b * S + s_row)) * 1024 + hh * 64;
#pragma unroll
        for (int dt = 0; dt < 4; ++dt)
          out[base + dt * 16 + lr] =
              (o_acc[ms][dt][r] + mo[row * 64 + dt * 16 + lr]) * inv;
      }
  }
}

// ---------------------------------------------------------------------------
extern "C" void kernel_launch(void* const* d_in, const int* in_sizes, int n_in,
                              void* d_out, int out_size, void* d_ws, size_t ws_size,
                              hipStream_t stream) {
  const float* q  = (const float*)d_in[0];
  const float* k  = (const float*)d_in[1];
  const float* v  = (const float*)d_in[2];
  const float* wq = (const float*)d_in[3];
  const float* bq = (const float*)d_in[4];
  const float* wk = (const float*)d_in[5];
  const float* bk = (const float*)d_in[6];
  const float* wv = (const float*)d_in[7];
  const float* bv = (const float*)d_in[8];

  bf16_t* ws  = (bf16_t*)d_ws;
  constexpr size_t MW = (size_t)1 << 20;
  constexpr size_t MX = (size_t)4096 * 1024;
  bf16_t* wtq = ws;
  bf16_t* wtk = wtq + MW;
  bf16_t* wtv = wtk + MW;
  bf16_t* xq  = wtv + MW;
  bf16_t* xk  = xq + MX;
  bf16_t* xv  = xk + MX;
  bf16_t* qhd = xv + MX;
  bf16_t* khd = qhd + MX;
  bf16_t* vtd = khd + MX;
  float* out  = (float*)d_out;

  prep<<<6912, 256, 0, stream>>>(q, k, v, wq, wk, wv,
                                 xq, xk, xv, wtq, wtk, wtv);
  proj_gemm<<<768, 256, 0, stream>>>(xq, xk, xv, wtq, wtk, wtv,
                                     bq, bk, bv, qhd, khd, vtd);
  attn<<<512, 512, 0, stream>>>(qhd, khd, vtd, out);
}